// Round 8
// baseline (532.974 us; speedup 1.0000x reference)
//
#include <hip/hip_runtime.h>
#include <hip/hip_bf16.h>

#define N_NODES 100000
#define N_EDGES 3200000
#define N_GRAPHS 64
#define NB 391                 // dst-buckets of 256 nodes (last has 160)
#define KCH 8192               // edges per binning block
#define NCHUNK ((N_EDGES + KCH - 1) / KCH)   // 391

__device__ __forceinline__ void atomAddF(float* p, float v) {
    unsafeAtomicAdd(p, v);
}

// bf16x2 pack/unpack (RTNE via __float2bfloat16)
__device__ __forceinline__ float lo2f(unsigned u) { return __uint_as_float(u << 16); }
__device__ __forceinline__ float hi2f(unsigned u) { return __uint_as_float(u & 0xFFFF0000u); }
__device__ __forceinline__ unsigned pack2(float a, float b) {
    unsigned ha = __bfloat16_as_ushort(__float2bfloat16(a));
    unsigned hb = __bfloat16_as_ushort(__float2bfloat16(b));
    return ha | (hb << 16);
}

// ---------------- CSR build ----------------
__global__ __launch_bounds__(512) void k_binCount(const int* __restrict__ dst,
                                                  int* __restrict__ gcount) {
    __shared__ int hist[NB];
    for (int t = threadIdx.x; t < NB; t += 512) hist[t] = 0;
    __syncthreads();
    int base = blockIdx.x * KCH;
    int cnt = min(KCH, N_EDGES - base);   // always divisible by 4
    const int4* d4 = (const int4*)(dst + base);
    for (int i = threadIdx.x; i < cnt / 4; i += 512) {
        int4 v = d4[i];
        atomicAdd(&hist[v.x >> 8], 1);
        atomicAdd(&hist[v.y >> 8], 1);
        atomicAdd(&hist[v.z >> 8], 1);
        atomicAdd(&hist[v.w >> 8], 1);
    }
    __syncthreads();
    for (int t = threadIdx.x; t < NB; t += 512)
        if (hist[t]) atomicAdd(&gcount[t], hist[t]);
}

__global__ __launch_bounds__(512) void k_scanB(const int* __restrict__ gcount,
                                               int* __restrict__ gbase,
                                               int* __restrict__ gcursor,
                                               int* __restrict__ rowptr) {
    __shared__ int s[512];
    int v = (threadIdx.x < NB) ? gcount[threadIdx.x] : 0;
    s[threadIdx.x] = v;
    __syncthreads();
    for (int off = 1; off < 512; off <<= 1) {
        int t = (threadIdx.x >= off) ? s[threadIdx.x - off] : 0;
        __syncthreads();
        s[threadIdx.x] += t;
        __syncthreads();
    }
    if (threadIdx.x < NB) {
        int e = s[threadIdx.x] - v;
        gbase[threadIdx.x] = e;
        gcursor[threadIdx.x] = e;
    }
    if (threadIdx.x == 0) rowptr[N_NODES] = N_EDGES;
}

// pass A: direct per-thread writes; per-bucket runs are contiguous (rbase+mypos)
__global__ __launch_bounds__(512) void k_binA(const int* __restrict__ src,
                                              const int* __restrict__ dst,
                                              int* __restrict__ gcursor,
                                              int* __restrict__ binned) {
    __shared__ int hist[512];
    __shared__ int rbase[512];
    hist[threadIdx.x] = 0;
    __syncthreads();
    int base = blockIdx.x * KCH;
    int cnt = min(KCH, N_EDGES - base);
    int myb[16], mypos[16];
    #pragma unroll
    for (int i = 0; i < 16; ++i) {
        int idx = i * 512 + threadIdx.x;
        if (idx < cnt) {
            int b = dst[base + idx] >> 8;
            myb[i] = b;
            mypos[i] = atomicAdd(&hist[b], 1);
        } else {
            myb[i] = -1;
        }
    }
    __syncthreads();
    int v = hist[threadIdx.x];
    if (threadIdx.x < NB && v > 0)
        rbase[threadIdx.x] = atomicAdd(&gcursor[threadIdx.x], v);
    __syncthreads();
    #pragma unroll
    for (int i = 0; i < 16; ++i) {
        if (myb[i] >= 0) {
            int e = base + i * 512 + threadIdx.x;
            int p = ((dst[e] & 255) << 24) | src[e];
            binned[rbase[myb[i]] + mypos[i]] = p;
        }
    }
}

// pass B: binned -> csr (node-sorted within bucket); emits rowptr + dinv
__global__ __launch_bounds__(512) void k_passB(const int* __restrict__ gbase,
                                               const int* __restrict__ binned,
                                               int* __restrict__ csr,
                                               int* __restrict__ rowptr,
                                               float* __restrict__ dinv) {
    int b = blockIdx.x;
    int rb = gbase[b];
    int re = (b == NB - 1) ? N_EDGES : gbase[b + 1];
    int cnt = re - rb;
    int nbase = b << 8;
    int nn = min(nbase + 256, N_NODES) - nbase;
    __shared__ int nhist[256];
    __shared__ int sc[256];
    __shared__ int ncur[256];
    for (int t = threadIdx.x; t < 256; t += 512) nhist[t] = 0;
    __syncthreads();
    for (int j = threadIdx.x; j < cnt; j += 512)
        atomicAdd(&nhist[((unsigned)binned[rb + j]) >> 24], 1);
    __syncthreads();
    if (threadIdx.x < 256) sc[threadIdx.x] = nhist[threadIdx.x];
    __syncthreads();
    for (int off = 1; off < 256; off <<= 1) {
        int t = (threadIdx.x < 256 && threadIdx.x >= off) ? sc[threadIdx.x - off] : 0;
        __syncthreads();
        if (threadIdx.x < 256) sc[threadIdx.x] += t;
        __syncthreads();
    }
    if (threadIdx.x < 256) {
        int e = sc[threadIdx.x] - nhist[threadIdx.x];
        ncur[threadIdx.x] = e;
        if (threadIdx.x < nn) {
            rowptr[nbase + threadIdx.x] = rb + e;
            dinv[nbase + threadIdx.x] = rsqrtf((float)nhist[threadIdx.x] + 1.0f);
        }
    }
    __syncthreads();
    for (int j = threadIdx.x; j < cnt; j += 512) {
        int p = binned[rb + j];                         // L2-hot re-read
        int slot = atomicAdd(&ncur[((unsigned)p) >> 24], 1);
        csr[rb + slot] = p;                             // confined to ~32KB window
    }
}

// -------- gather: out = di*(sum A'[s] + A'[n]) (+bias,relu); 8-way MLP --------
template<int LOGW, bool BIAS_RELU, bool OB, bool PRE>
__global__ void __launch_bounds__(256) k_gatherB(
        const int* __restrict__ rowptr, const int* __restrict__ csr,
        const unsigned* __restrict__ in /* bf16x2 pairs, prescaled */,
        const float* __restrict__ dinv,
        const float* __restrict__ ba, const float* __restrict__ bb,
        void* __restrict__ out) {
    constexpr int W4 = (1 << LOGW) / 4;   // lanes per node
    constexpr int NPB = 256 / W4;
    int n = blockIdx.x * NPB + (threadIdx.x / W4);
    int sub = threadIdx.x % W4;
    const uint2* in2 = (const uint2*)in;
    uint2 u = in2[(size_t)n * W4 + sub];              // self term A'[n]
    float4 acc = make_float4(lo2f(u.x), hi2f(u.x), lo2f(u.y), hi2f(u.y));
    int j = rowptr[n], end = rowptr[n + 1];
    for (; j + 8 <= end; j += 8) {
        int s0 = csr[j] & 0xFFFFFF;
        int s1 = csr[j + 1] & 0xFFFFFF;
        int s2 = csr[j + 2] & 0xFFFFFF;
        int s3 = csr[j + 3] & 0xFFFFFF;
        int s4 = csr[j + 4] & 0xFFFFFF;
        int s5 = csr[j + 5] & 0xFFFFFF;
        int s6 = csr[j + 6] & 0xFFFFFF;
        int s7 = csr[j + 7] & 0xFFFFFF;
        uint2 v0 = in2[(size_t)s0 * W4 + sub];
        uint2 v1 = in2[(size_t)s1 * W4 + sub];
        uint2 v2 = in2[(size_t)s2 * W4 + sub];
        uint2 v3 = in2[(size_t)s3 * W4 + sub];
        uint2 v4 = in2[(size_t)s4 * W4 + sub];
        uint2 v5 = in2[(size_t)s5 * W4 + sub];
        uint2 v6 = in2[(size_t)s6 * W4 + sub];
        uint2 v7 = in2[(size_t)s7 * W4 + sub];
        acc.x += ((lo2f(v0.x) + lo2f(v1.x)) + (lo2f(v2.x) + lo2f(v3.x)))
               + ((lo2f(v4.x) + lo2f(v5.x)) + (lo2f(v6.x) + lo2f(v7.x)));
        acc.y += ((hi2f(v0.x) + hi2f(v1.x)) + (hi2f(v2.x) + hi2f(v3.x)))
               + ((hi2f(v4.x) + hi2f(v5.x)) + (hi2f(v6.x) + hi2f(v7.x)));
        acc.z += ((lo2f(v0.y) + lo2f(v1.y)) + (lo2f(v2.y) + lo2f(v3.y)))
               + ((lo2f(v4.y) + lo2f(v5.y)) + (lo2f(v6.y) + lo2f(v7.y)));
        acc.w += ((hi2f(v0.y) + hi2f(v1.y)) + (hi2f(v2.y) + hi2f(v3.y)))
               + ((hi2f(v4.y) + hi2f(v5.y)) + (hi2f(v6.y) + hi2f(v7.y)));
    }
    if (j + 4 <= end) {
        int s0 = csr[j] & 0xFFFFFF;
        int s1 = csr[j + 1] & 0xFFFFFF;
        int s2 = csr[j + 2] & 0xFFFFFF;
        int s3 = csr[j + 3] & 0xFFFFFF;
        uint2 v0 = in2[(size_t)s0 * W4 + sub];
        uint2 v1 = in2[(size_t)s1 * W4 + sub];
        uint2 v2 = in2[(size_t)s2 * W4 + sub];
        uint2 v3 = in2[(size_t)s3 * W4 + sub];
        acc.x += (lo2f(v0.x) + lo2f(v1.x)) + (lo2f(v2.x) + lo2f(v3.x));
        acc.y += (hi2f(v0.x) + hi2f(v1.x)) + (hi2f(v2.x) + hi2f(v3.x));
        acc.z += (lo2f(v0.y) + lo2f(v1.y)) + (lo2f(v2.y) + lo2f(v3.y));
        acc.w += (hi2f(v0.y) + hi2f(v1.y)) + (hi2f(v2.y) + hi2f(v3.y));
        j += 4;
    }
    for (; j < end; ++j) {
        int s = csr[j] & 0xFFFFFF;
        uint2 v = in2[(size_t)s * W4 + sub];
        acc.x += lo2f(v.x);
        acc.y += hi2f(v.x);
        acc.z += lo2f(v.y);
        acc.w += hi2f(v.y);
    }
    float di = dinv[n];
    acc.x *= di; acc.y *= di; acc.z *= di; acc.w *= di;
    if (BIAS_RELU) {
        constexpr int H = (1 << LOGW) / 2;
        int d = sub * 4;
        const float* bp = (d < H) ? (ba + d) : (bb + d - H);
        acc.x = fmaxf(acc.x + bp[0], 0.0f);
        acc.y = fmaxf(acc.y + bp[1], 0.0f);
        acc.z = fmaxf(acc.z + bp[2], 0.0f);
        acc.w = fmaxf(acc.w + bp[3], 0.0f);
    }
    if (PRE) {
        acc.x *= di; acc.y *= di; acc.z *= di; acc.w *= di;
    }
    if (OB) {
        ((uint2*)out)[(size_t)n * W4 + sub] =
            make_uint2(pack2(acc.x, acc.y), pack2(acc.z, acc.w));
    } else {
        ((float4*)out)[(size_t)n * W4 + sub] = acc;
    }
}

// ------- dense: two-branch matmul, 4 outputs/thread; optional dinv out-scale -------
template<int IN_W, int OUT_HALF, int A_OFF, int A_W, int B_OFF, bool BR, bool OB, bool DS>
__global__ void k_dense4(const float* __restrict__ in,
                         const float* __restrict__ Wa, const float* __restrict__ ba,
                         const float* __restrict__ Wb, const float* __restrict__ bb,
                         const float* __restrict__ dinv,
                         void* __restrict__ out) {
    __shared__ float sWa[A_W * OUT_HALF];
    __shared__ float sWb[A_W * OUT_HALF];
    __shared__ float sba[OUT_HALF];
    __shared__ float sbb[OUT_HALF];
    for (int t = threadIdx.x; t < A_W * OUT_HALF; t += 256) {
        sWa[t] = Wa[t];
        sWb[t] = Wb[t];
    }
    if (BR && threadIdx.x < OUT_HALF) {
        sba[threadIdx.x] = ba[threadIdx.x];
        sbb[threadIdx.x] = bb[threadIdx.x];
    }
    __syncthreads();
    constexpr int TPN = OUT_HALF / 2;            // threads per node
    int idx = blockIdx.x * 256 + threadIdx.x;    // exact grid: N*TPN
    int n = idx / TPN;
    int q = idx % TPN;
    bool isB = (q * 4) >= OUT_HALF;
    int dd = q * 4 - (isB ? OUT_HALF : 0);
    const float* sW = isB ? sWb : sWa;
    int ko = isB ? B_OFF : A_OFF;
    float4 acc;
    if (BR) {
        const float* bp = isB ? (sbb + dd) : (sba + dd);
        acc = make_float4(bp[0], bp[1], bp[2], bp[3]);
    } else {
        acc = make_float4(0.f, 0.f, 0.f, 0.f);
    }
    const float* row = in + (size_t)n * IN_W + ko;
    #pragma unroll
    for (int k = 0; k < A_W; ++k) {
        float r = row[k];
        float4 wv = *(const float4*)&sW[k * OUT_HALF + dd];
        acc.x = fmaf(r, wv.x, acc.x);
        acc.y = fmaf(r, wv.y, acc.y);
        acc.z = fmaf(r, wv.z, acc.z);
        acc.w = fmaf(r, wv.w, acc.w);
    }
    if (BR) {
        acc.x = fmaxf(acc.x, 0.f); acc.y = fmaxf(acc.y, 0.f);
        acc.z = fmaxf(acc.z, 0.f); acc.w = fmaxf(acc.w, 0.f);
    }
    if (DS) {
        float dn = dinv[n];
        acc.x *= dn; acc.y *= dn; acc.z *= dn; acc.w *= dn;
    }
    if (OB) {
        ((uint2*)out)[idx] = make_uint2(pack2(acc.x, acc.y), pack2(acc.z, acc.w));
    } else {
        ((float4*)out)[idx] = acc;
    }
}

// ------- dense3 + mean-pool fused: h3 never materialized -------
// 8 nodes/block (TPN=32); LDS per-graph accumulators (<=2 graphs per block,
// global-atomic fallback if more); flush <=256 atomics/block.
__global__ void __launch_bounds__(256) k_dense3pool(
        const float* __restrict__ in,
        const float* __restrict__ Wa, const float* __restrict__ ba,
        const float* __restrict__ Wb, const float* __restrict__ bb,
        const int* __restrict__ batch,
        float* __restrict__ pool) {
    __shared__ float sWa[32 * 64];
    __shared__ float sWb[32 * 64];
    __shared__ float sba[64];
    __shared__ float sbb[64];
    __shared__ float sacc[2][128];
    for (int t = threadIdx.x; t < 32 * 64; t += 256) {
        sWa[t] = Wa[t];
        sWb[t] = Wb[t];
    }
    if (threadIdx.x < 64) {
        sba[threadIdx.x] = ba[threadIdx.x];
        sbb[threadIdx.x] = bb[threadIdx.x];
    }
    sacc[0][threadIdx.x & 127] = 0.0f;   // covers [2][128] with 256 threads
    sacc[1][threadIdx.x & 127] = 0.0f;
    __syncthreads();
    int idx = blockIdx.x * 256 + threadIdx.x;    // grid: N*32/256
    int n = idx / 32;
    int q = idx % 32;
    bool isB = q >= 16;
    int dd = q * 4 - (isB ? 64 : 0);
    const float* sW = isB ? sWb : sWa;
    const float* bp = isB ? (sbb + dd) : (sba + dd);
    float4 acc = make_float4(bp[0], bp[1], bp[2], bp[3]);
    const float* row = in + (size_t)n * 64 + (isB ? 32 : 0);
    #pragma unroll
    for (int k = 0; k < 32; ++k) {
        float r = row[k];
        float4 wv = *(const float4*)&sW[k * 64 + dd];
        acc.x = fmaf(r, wv.x, acc.x);
        acc.y = fmaf(r, wv.y, acc.y);
        acc.z = fmaf(r, wv.z, acc.z);
        acc.w = fmaf(r, wv.w, acc.w);
    }
    acc.x = fmaxf(acc.x, 0.f); acc.y = fmaxf(acc.y, 0.f);
    acc.z = fmaxf(acc.z, 0.f); acc.w = fmaxf(acc.w, 0.f);
    int g0 = batch[blockIdx.x * 8];
    int gn = batch[n];
    int gsel = gn - g0;
    int d = q * 4;                               // global dim 0..127
    if (gsel <= 1) {
        atomicAdd(&sacc[gsel][d + 0], acc.x);
        atomicAdd(&sacc[gsel][d + 1], acc.y);
        atomicAdd(&sacc[gsel][d + 2], acc.z);
        atomicAdd(&sacc[gsel][d + 3], acc.w);
    } else {                                     // ultra-rare safety net
        atomAddF(&pool[gn * 128 + d + 0], acc.x);
        atomAddF(&pool[gn * 128 + d + 1], acc.y);
        atomAddF(&pool[gn * 128 + d + 2], acc.z);
        atomAddF(&pool[gn * 128 + d + 3], acc.w);
    }
    __syncthreads();
    int gs = threadIdx.x >> 7;
    int dj = threadIdx.x & 127;
    float v = sacc[gs][dj];
    if (v != 0.0f) atomAddF(&pool[(g0 + gs) * 128 + dj], v);
}

// ------- final: counts via binary search + reparameterize -------
__global__ void k_final(const float* __restrict__ pool, const int* __restrict__ batch,
                        const float* __restrict__ eps, float* __restrict__ zbuf,
                        float* __restrict__ out_mu, float* __restrict__ out_lv) {
    int idx = blockIdx.x * 256 + threadIdx.x;   // 4096 threads
    int g = idx >> 6;
    int bounds[2];
    #pragma unroll
    for (int t = 0; t < 2; ++t) {
        int target = g + t;
        int lo = 0, hi = N_NODES;
        while (lo < hi) {
            int mid = (lo + hi) >> 1;
            if (batch[mid] < target) lo = mid + 1; else hi = mid;
        }
        bounds[t] = lo;
    }
    float c = fmaxf((float)(bounds[1] - bounds[0]), 1.0f);
    float mu = pool[g * 128 + (idx & 63)] / c;
    float lv = pool[g * 128 + 64 + (idx & 63)] / c;
    zbuf[idx] = mu + eps[idx] * __expf(0.5f * lv);
    out_mu[idx] = mu;
    out_lv[idx] = lv;
}

// ---------------- decode: sigmoid(z @ Wfc + bfc) ----------------
__global__ void __launch_bounds__(256) k_decode(const float* __restrict__ zbuf,
                                                const float* __restrict__ Wfc,
                                                const float* __restrict__ bfc,
                                                float* __restrict__ out) {
    __shared__ float sz[64 * 64];
    for (int t = threadIdx.x; t < 4096; t += 256) sz[t] = zbuf[t];
    __syncthreads();
    int j = blockIdx.x * 256 + threadIdx.x;
    float bias = bfc[j];
    float acc[64];
    #pragma unroll
    for (int g = 0; g < 64; ++g) acc[g] = bias;
    #pragma unroll 4
    for (int k4 = 0; k4 < 16; ++k4) {
        float w0 = Wfc[(k4 * 4 + 0) * 160000 + j];
        float w1 = Wfc[(k4 * 4 + 1) * 160000 + j];
        float w2 = Wfc[(k4 * 4 + 2) * 160000 + j];
        float w3 = Wfc[(k4 * 4 + 3) * 160000 + j];
        #pragma unroll
        for (int g = 0; g < 64; ++g) {
            float4 zv = *(const float4*)&sz[g * 64 + k4 * 4];
            acc[g] = fmaf(zv.x, w0, acc[g]);
            acc[g] = fmaf(zv.y, w1, acc[g]);
            acc[g] = fmaf(zv.z, w2, acc[g]);
            acc[g] = fmaf(zv.w, w3, acc[g]);
        }
    }
    #pragma unroll
    for (int g = 0; g < 64; ++g) {
        float s = 1.0f / (1.0f + __expf(-acc[g]));
        out[g * 160000 + j] = s;
    }
}

extern "C" void kernel_launch(void* const* d_in, const int* in_sizes, int n_in,
                              void* d_out, int out_size, void* d_ws, size_t ws_size,
                              hipStream_t stream) {
    const float* x     = (const float*)d_in[0];
    const int*   ei    = (const int*)d_in[1];
    const int*   batch = (const int*)d_in[2];
    const float *W1m = (const float*)d_in[3],  *b1m = (const float*)d_in[4];
    const float *W2m = (const float*)d_in[5],  *b2m = (const float*)d_in[6];
    const float *W3m = (const float*)d_in[7],  *b3m = (const float*)d_in[8];
    const float *W1l = (const float*)d_in[9],  *b1l = (const float*)d_in[10];
    const float *W2l = (const float*)d_in[11], *b2l = (const float*)d_in[12];
    const float *W3l = (const float*)d_in[13], *b3l = (const float*)d_in[14];
    const float *Wfc = (const float*)d_in[15], *bfc = (const float*)d_in[16];
    const float *eps = (const float*)d_in[17];

    const int* srcv = ei;
    const int* dstv = ei + N_EDGES;

    char* w = (char*)d_ws;
    auto alloc = [&](size_t bytes) -> char* {
        char* p = w;
        w += (bytes + 255) & ~(size_t)255;
        return p;
    };
    int*   gcount = (int*)  alloc((size_t)NB * 4);
    int*   gbase  = (int*)  alloc((size_t)NB * 4);
    int*   gcursor= (int*)  alloc((size_t)NB * 4);
    int*   rowptr = (int*)  alloc((size_t)(N_NODES + 1) * 4);
    float* dinv   = (float*)alloc((size_t)N_NODES * 4);
    float* pool   = (float*)alloc((size_t)N_GRAPHS * 128 * 4);
    float* zbuf   = (float*)alloc((size_t)N_GRAPHS * 64 * 4);
    // Arena (76.8 MB): A (64N f32) | B (64N f32) | csr (32N) | binned (32N)
    //   A: dinv*xW bf16 -> A*h1 f32 -> A*h2 f32
    //   B: dinv*h1 bf16 -> dinv*h2 bf16
    float* arena = (float*)alloc((size_t)N_NODES * 192 * 4);
    float* A      = arena;
    float* B      = arena + (size_t)N_NODES * 64;
    int*   csr    = (int*)(arena + (size_t)N_NODES * 128);
    int*   binned = (int*)(arena + (size_t)N_NODES * 160);

    float* out    = (float*)d_out;
    float* out_mu = out + 10240000;
    float* out_lv = out + 10240000 + 4096;

    hipMemsetAsync(gcount, 0, (size_t)NB * 4, stream);
    hipMemsetAsync(pool, 0, (size_t)N_GRAPHS * 128 * 4, stream);

    // ---- CSR build (binned, stage-free) ----
    k_binCount<<<NCHUNK, 512, 0, stream>>>(dstv, gcount);
    k_scanB<<<1, 512, 0, stream>>>(gcount, gbase, gcursor, rowptr);
    k_binA<<<NCHUNK, 512, 0, stream>>>(srcv, dstv, gcursor, binned);
    k_passB<<<NB, 512, 0, stream>>>(gbase, binned, csr, rowptr, dinv);

    // ---- L1: dense -> dinv*xW bf16; gather w32 -> dinv*relu(...) bf16 ----
    k_dense4<64, 16, 0, 64, 0, false, true, true><<<N_NODES * 8 / 256, 256, 0, stream>>>(
        x, W1m, b1m, W1l, b1l, dinv, A);
    k_gatherB<5, true, true, true><<<N_NODES / 32, 256, 0, stream>>>(
        rowptr, csr, (const unsigned*)A, dinv, b1m, b1l, B);

    // ---- L2: gather w32 -> f32 agg; dense 16->32 x2 -> dinv*relu bf16 ----
    k_gatherB<5, false, false, false><<<N_NODES / 32, 256, 0, stream>>>(
        rowptr, csr, (const unsigned*)B, dinv, b1m, b1l, A);
    k_dense4<32, 32, 0, 16, 16, true, true, true><<<N_NODES * 16 / 256, 256, 0, stream>>>(
        A, W2m, b2m, W2l, b2l, dinv, B);

    // ---- L3: gather w64 -> f32 agg; dense3+pool fused ----
    k_gatherB<6, false, false, false><<<N_NODES / 16, 256, 0, stream>>>(
        rowptr, csr, (const unsigned*)B, dinv, b1m, b1l, A);
    k_dense3pool<<<N_NODES * 32 / 256, 256, 0, stream>>>(
        A, W3m, b3m, W3l, b3l, batch, pool);

    // ---- reparameterize (counts fused) ----
    k_final<<<16, 256, 0, stream>>>(pool, batch, eps, zbuf, out_mu, out_lv);

    // ---- decode ----
    k_decode<<<625, 256, 0, stream>>>(zbuf, Wfc, bfc, out);
}